// Round 3
// baseline (483.292 us; speedup 1.0000x reference)
//
#include <hip/hip_runtime.h>
#include <cstddef>

// Problem constants
#define BB 64
#define TT 512
#define DD 1024
#define VV 28

// ---------------------------------------------------------------------------
// K1 (split-K over d): block (b, tch, ds) computes, for 64 t-rows and its
// 256-d slice (NDS=4):
//   hU_part[ds][t+1][b][v] += x[b,t,dslice] @ Uo[dslice,v]
//   part[b][tch*2+half][dslice] = 32-row sums of x (f32-exact rowsum partials)
// Grid: 512*NDS blocks, 256 threads. LDS: xs[64][68] = 17.4 KB -> 8 blocks/CU,
// 32 waves/CU (the round-2 kernel was 2 blocks/CU => 480 GB/s duty-cycle wall).
// Uo read from global: wave-uniform address (vg = tid>>6) -> 1 L1 line/load.
// ---------------------------------------------------------------------------
template <int NDS>
__global__ __launch_bounds__(256, 8) void k1_hU_rowsum(
    const float* __restrict__ x, const float* __restrict__ Uo,
    float* __restrict__ hUp, float* __restrict__ part) {
  constexpr int DPB = DD / NDS;   // d's per block
  constexpr int NCH = DPB / 64;   // 64-d chunks per block
  constexpr int LG  = (NDS == 4) ? 2 : 0;
  __shared__ float xs[64][68];    // stride 68: b128 reads 2-way (free) per m136
  const int g   = blockIdx.x;
  const int ds  = g & (NDS - 1);
  const int g2  = g >> LG;
  const int tch = g2 & 7;
  const int b   = g2 >> 3;
  const int t0  = tch << 6;
  const int tid = threadIdx.x;
  const int r2  = tid & 63;       // compute: row (lane == row)
  const int vg  = tid >> 6;       // compute: wave id -> v base 8*vg (wave-uniform)
  const int offb = (vg == 3) ? 0 : 4;  // vg3 covers v24..27 only: clamp 2nd
                                       // float4 to avoid OOB reads past Uo
  float acc[8];
#pragma unroll
  for (int j = 0; j < 8; ++j) acc[j] = 0.f;
  const float* xbase = x + (size_t)(b * TT + t0) * DD + ds * DPB;
  const int rcol  = tid & 63;     // rowsum: column within chunk
  const int rhalf = tid >> 6;     // rowsum: threads<128 -> half 0/1 (32 rows)

  for (int c = 0; c < NCH; ++c) {
    const int d0 = c << 6;  // local d offset within block's slice
    __syncthreads();        // previous chunk's reads (compute + rowsum) done
    // stage 64 rows x 64 d: 4 float4/thread, 256B contiguous per row-segment
#pragma unroll
    for (int i = 0; i < 4; ++i) {
      const int f   = tid + (i << 8);
      const int row = f >> 4;
      const int col = (f & 15) << 2;
      const float4 vx = *reinterpret_cast<const float4*>(
          xbase + (size_t)row * DD + d0 + col);
      *reinterpret_cast<float4*>(&xs[row][col]) = vx;
    }
    __syncthreads();
    const float* up = Uo + (size_t)(ds * DPB + d0) * VV + (vg << 3);
#pragma unroll 2
    for (int dd = 0; dd < 64; dd += 4) {
      const float4 xv = *reinterpret_cast<const float4*>(&xs[r2][dd]);
      const float xq[4] = {xv.x, xv.y, xv.z, xv.w};
#pragma unroll
      for (int q = 0; q < 4; ++q) {
        const float* ur = up + (size_t)(dd + q) * VV;  // 16B-aligned
        const float4 wa = *reinterpret_cast<const float4*>(ur);
        const float4 wb = *reinterpret_cast<const float4*>(ur + offb);
        acc[0] = fmaf(xq[q], wa.x, acc[0]);
        acc[1] = fmaf(xq[q], wa.y, acc[1]);
        acc[2] = fmaf(xq[q], wa.z, acc[2]);
        acc[3] = fmaf(xq[q], wa.w, acc[3]);
        acc[4] = fmaf(xq[q], wb.x, acc[4]);
        acc[5] = fmaf(xq[q], wb.y, acc[5]);
        acc[6] = fmaf(xq[q], wb.z, acc[6]);
        acc[7] = fmaf(xq[q], wb.w, acc[7]);
      }
    }
    // rowsum partials (reads xs before next chunk's barrier)
    if (tid < 128) {
      float s = 0.f;
      const int rbase = rhalf << 5;
#pragma unroll 8
      for (int r = 0; r < 32; ++r) s += xs[rbase + r][rcol];
      part[(size_t)(b * 16 + tch * 2 + rhalf) * DD + ds * DPB + d0 + rcol] = s;
    }
  }
  // epilogue: row t feeds step t+1; t = T-1 discarded
  const int t = t0 + r2;
  if (t + 1 < TT) {
    float* o = hUp + (size_t)ds * TT * BB * VV +
               ((size_t)(t + 1) * BB + b) * VV + (vg << 3);
    *reinterpret_cast<float4*>(o) = make_float4(acc[0], acc[1], acc[2], acc[3]);
    if (vg < 3)
      *reinterpret_cast<float4*>(o + 4) =
          make_float4(acc[4], acc[5], acc[6], acc[7]);
  }
}

// ---------------------------------------------------------------------------
// K2: ctx[b][v] = (sum_t x[b,t,:]) @ Co[:,v];  ew[j] = emb_table[j,:] @ Wo
// Grid: 64 blocks x 256 threads. (unchanged from passing round-2 kernel)
// ---------------------------------------------------------------------------
__global__ __launch_bounds__(256) void k2_ctx_ew(
    const float* __restrict__ part, const float* __restrict__ Co,
    const float* __restrict__ Wo, const float* __restrict__ emb,
    float* __restrict__ ctx, float* __restrict__ ew) {
  __shared__ float rs[DD];
  __shared__ float red[8][32];
  const int b = blockIdx.x;
  const int tid = threadIdx.x;
  for (int d = tid; d < DD; d += 256) {
    float s = 0.f;
#pragma unroll
    for (int k = 0; k < 16; ++k) s += part[(size_t)(b * 16 + k) * DD + d];
    rs[d] = s;
  }
  __syncthreads();
  const int v = tid & 31, seg = tid >> 5;
  float pa = 0.f;
  if (v < VV) {
    const float* cp = Co + (size_t)(seg * 128) * VV + v;
    const float* rp = &rs[seg * 128];
#pragma unroll 4
    for (int d = 0; d < 128; ++d) pa = fmaf(rp[d], cp[(size_t)d * VV], pa);
  }
  red[seg][v] = pa;
  __syncthreads();
  if (tid < 32) {
    float s = 0.f;
#pragma unroll
    for (int k = 0; k < 8; ++k) s += red[k][tid];
    if (tid < VV) ctx[b * VV + tid] = s;
  }
  if (b == 0 && tid >= 64 && tid < 64 + VV) {
    const int j = tid - 64;
    float s = 0.f;
#pragma unroll
    for (int k = 0; k < VV; ++k) s = fmaf(emb[j * VV + k], Wo[k], s);
    ew[j] = s;
  }
}

// ---------------------------------------------------------------------------
// K3: the scan. 1792 independent (b,v) chains; per-step dependent work is
// select+compare (both sigmoid candidates independent of state). With split-K,
// h = sum of NDS partial planes (independent loads, pipeline under unroll 8).
// ---------------------------------------------------------------------------
template <int NDS>
__global__ __launch_bounds__(64) void k3_scan(
    const float* __restrict__ hU, const float* __restrict__ ctx,
    const float* __restrict__ ew, float* __restrict__ out) {
  const int gid = blockIdx.x * 64 + threadIdx.x;  // 0..1791
  const int b = gid / VV;
  const int v = gid - b * VV;
  const float ctxv = ctx[b * VV + v];
  const float e0 = ew[0] + ctxv;
  const float e1 = ew[1] + ctxv;
  constexpr size_t PL = (size_t)TT * BB * VV;  // plane stride
  const float* hp = hU + (size_t)b * VV + v;
  float* op = out + (size_t)b * TT * VV + v;
  bool s;
  {
    // t = 0: h_prev = 0 and y_prev = 0 -> ew[0], no hU term
    const float y = 1.f / (1.f + expf(-e0));
    s = (y == 1.0f);
    op[0] = y;
  }
#pragma unroll 8
  for (int t = 1; t < TT; ++t) {
    float h = 0.f;
#pragma unroll
    for (int p = 0; p < NDS; ++p)
      h += hp[(size_t)p * PL + (size_t)t * (BB * VV)];
    const float c0 = 1.f / (1.f + expf(-(e0 + h)));
    const float c1 = 1.f / (1.f + expf(-(e1 + h)));
    const float y = s ? c1 : c0;
    s = (y == 1.0f);
    op[(size_t)t * VV] = y;
  }
}

// ---------------------------------------------------------------------------
extern "C" void kernel_launch(void* const* d_in, const int* in_sizes, int n_in,
                              void* d_out, int out_size, void* d_ws, size_t ws_size,
                              hipStream_t stream) {
  const float* x   = (const float*)d_in[0];
  // d_in[1]=Wa, d_in[2]=Ua, d_in[3]=Va dead (softmax over size-1 axis == 1)
  const float* Wo  = (const float*)d_in[4];
  const float* Uo  = (const float*)d_in[5];
  const float* Co  = (const float*)d_in[6];
  const float* emb = (const float*)d_in[7];
  float* out = (float*)d_out;

  const size_t PL = (size_t)TT * BB * VV;          // 917504 floats / plane
  const size_t PART = (size_t)BB * 16 * DD;        // 1048576 floats
  const size_t need4 = (4 * PL + PART + BB * VV + 32) * sizeof(float);  // ~18.9MB

  float* ws = (float*)d_ws;
  if (ws_size >= need4) {
    float* hUp  = ws;
    float* part = hUp + 4 * PL;
    float* ctx  = part + PART;
    float* ewp  = ctx + BB * VV;
    k1_hU_rowsum<4><<<512 * 4, 256, 0, stream>>>(x, Uo, hUp, part);
    k2_ctx_ew<<<BB, 256, 0, stream>>>(part, Co, Wo, emb, ctx, ewp);
    k3_scan<4><<<28, 64, 0, stream>>>(hUp, ctx, ewp, out);
  } else {
    float* hUp  = ws;
    float* part = hUp + PL;
    float* ctx  = part + PART;
    float* ewp  = ctx + BB * VV;
    k1_hU_rowsum<1><<<512, 256, 0, stream>>>(x, Uo, hUp, part);
    k2_ctx_ew<<<BB, 256, 0, stream>>>(part, Co, Wo, emb, ctx, ewp);
    k3_scan<1><<<28, 64, 0, stream>>>(hUp, ctx, ewp, out);
  }
}

// Round 4
// 378.658 us; speedup vs baseline: 1.2763x; 1.2763x over previous
//
#include <hip/hip_runtime.h>
#include <cstddef>

// Problem constants
#define BB 64
#define TT 512
#define DD 1024
#define VV 28

// ---------------------------------------------------------------------------
// K1 (split-K over d): block (b, tch, ds) computes, for 64 t-rows and its
// 256-d slice (NDS=4):
//   hU_part[ds][t+1][b][v] = x[b,t,dslice] @ Uo[dslice,v]
//   part[b*16 + tch*2 + half][dslice] = 32-row sums of x (f32-exact)
// Round-3 lesson: wave-uniform Uo GLOBAL loads in the FMA loop were a serial
// ~200cy-latency chain (VGPR=32 -> MLP~1) = the whole 188us. Uo now staged
// per-chunk into LDS (Wl[64][32], broadcast reads, conflict-free). No global
// loads in the hot loop.
// LDS 25.6KB -> 6 blocks/CU, 24 waves/CU.
// ---------------------------------------------------------------------------
template <int NDS>
__global__ __launch_bounds__(256, 8) void k1_hU_rowsum(
    const float* __restrict__ x, const float* __restrict__ Uo,
    float* __restrict__ hUp, float* __restrict__ part) {
  constexpr int DPB = DD / NDS;   // d's per block
  constexpr int NCH = DPB / 64;   // 64-d chunks per block
  constexpr int LG  = (NDS == 4) ? 2 : 0;
  __shared__ float xs[64][68];    // stride 68: b128 col-reads 2-way (free, m136)
  __shared__ float Wl[64][32];    // Uo chunk, zero-padded cols 28..31
  const int g   = blockIdx.x;
  const int ds  = g & (NDS - 1);
  const int g2  = g >> LG;
  const int tch = g2 & 7;
  const int b   = g2 >> 3;
  const int t0  = tch << 6;
  const int tid = threadIdx.x;
  const int r2  = tid & 63;       // compute: row (lane == row)
  const int vg  = tid >> 6;       // compute: wave id -> v base 8*vg
  const int dbase = ds * DPB;
  float acc[8];
#pragma unroll
  for (int j = 0; j < 8; ++j) acc[j] = 0.f;
  const float* xbase = x + (size_t)(b * TT + t0) * DD + dbase;
  const int rcol  = tid & 63;     // rowsum: column within chunk
  const int rhalf = tid >> 6;     // rowsum: (tid<128) half 0/1 -> 32 rows each

  for (int c = 0; c < NCH; ++c) {
    const int d0 = c << 6;        // local d offset within block's slice
    __syncthreads();              // previous chunk's reads done
    // stage x tile 64 rows x 64 d: 4 float4/thread, 256B runs per row-segment
#pragma unroll
    for (int i = 0; i < 4; ++i) {
      const int f   = tid + (i << 8);
      const int row = f >> 4;
      const int col = (f & 15) << 2;
      *reinterpret_cast<float4*>(&xs[row][col]) =
          *reinterpret_cast<const float4*>(xbase + (size_t)row * DD + d0 + col);
    }
    // stage Uo chunk 64 rows x 28 (pad to 32): 8 floats/thread, coalesced
#pragma unroll
    for (int k = 0; k < 8; ++k) {
      const int idx = tid + (k << 8);   // 0..2047
      const int row = idx >> 5, col = idx & 31;
      Wl[row][col] =
          (col < VV) ? Uo[(size_t)(dbase + d0 + row) * VV + col] : 0.f;
    }
    __syncthreads();
    // hot loop: LDS only. xs per-lane b128; Wl rows wave-uniform -> broadcast
#pragma unroll 2
    for (int dd = 0; dd < 64; dd += 4) {
      const float4 xv = *reinterpret_cast<const float4*>(&xs[r2][dd]);
      const float xq[4] = {xv.x, xv.y, xv.z, xv.w};
#pragma unroll
      for (int q = 0; q < 4; ++q) {
        const float* wr = &Wl[dd + q][vg << 3];
        const float4 wa = *reinterpret_cast<const float4*>(wr);
        const float4 wb = *reinterpret_cast<const float4*>(wr + 4);  // vg3: pad zeros
        acc[0] = fmaf(xq[q], wa.x, acc[0]);
        acc[1] = fmaf(xq[q], wa.y, acc[1]);
        acc[2] = fmaf(xq[q], wa.z, acc[2]);
        acc[3] = fmaf(xq[q], wa.w, acc[3]);
        acc[4] = fmaf(xq[q], wb.x, acc[4]);
        acc[5] = fmaf(xq[q], wb.y, acc[5]);
        acc[6] = fmaf(xq[q], wb.z, acc[6]);
        acc[7] = fmaf(xq[q], wb.w, acc[7]);
      }
    }
    // rowsum partials (reads xs before next chunk's barrier); conflict-free
    if (tid < 128) {
      float s = 0.f;
      const int rbase = rhalf << 5;
#pragma unroll 8
      for (int r = 0; r < 32; ++r) s += xs[rbase + r][rcol];
      part[(size_t)(b * 16 + tch * 2 + rhalf) * DD + dbase + d0 + rcol] = s;
    }
  }
  // epilogue: row t feeds step t+1; t = T-1 discarded
  const int t = t0 + r2;
  if (t + 1 < TT) {
    float* o = hUp + (size_t)ds * TT * BB * VV +
               ((size_t)(t + 1) * BB + b) * VV + (vg << 3);
    *reinterpret_cast<float4*>(o) = make_float4(acc[0], acc[1], acc[2], acc[3]);
    if (vg < 3)
      *reinterpret_cast<float4*>(o + 4) =
          make_float4(acc[4], acc[5], acc[6], acc[7]);
  }
}

// ---------------------------------------------------------------------------
// K2: ctx[b][v] = (sum_t x[b,t,:]) @ Co[:,v];  ew[j] = emb_table[j,:] @ Wo
// Grid: 64 blocks x 256 threads. (unchanged; passes, not the bottleneck)
// ---------------------------------------------------------------------------
__global__ __launch_bounds__(256) void k2_ctx_ew(
    const float* __restrict__ part, const float* __restrict__ Co,
    const float* __restrict__ Wo, const float* __restrict__ emb,
    float* __restrict__ ctx, float* __restrict__ ew) {
  __shared__ float rs[DD];
  __shared__ float red[8][32];
  const int b = blockIdx.x;
  const int tid = threadIdx.x;
  for (int d = tid; d < DD; d += 256) {
    float s = 0.f;
#pragma unroll
    for (int k = 0; k < 16; ++k) s += part[(size_t)(b * 16 + k) * DD + d];
    rs[d] = s;
  }
  __syncthreads();
  const int v = tid & 31, seg = tid >> 5;
  float pa = 0.f;
  if (v < VV) {
    const float* cp = Co + (size_t)(seg * 128) * VV + v;
    const float* rp = &rs[seg * 128];
#pragma unroll 4
    for (int d = 0; d < 128; ++d) pa = fmaf(rp[d], cp[(size_t)d * VV], pa);
  }
  red[seg][v] = pa;
  __syncthreads();
  if (tid < 32) {
    float s = 0.f;
#pragma unroll
    for (int k = 0; k < 8; ++k) s += red[k][tid];
    if (tid < VV) ctx[b * VV + tid] = s;
  }
  if (b == 0 && tid >= 64 && tid < 64 + VV) {
    const int j = tid - 64;
    float s = 0.f;
#pragma unroll
    for (int k = 0; k < VV; ++k) s = fmaf(emb[j * VV + k], Wo[k], s);
    ew[j] = s;
  }
}

// ---------------------------------------------------------------------------
// K3: the scan. 1792 independent (b,v) chains; per-step dependent work is
// select+compare (both sigmoid candidates independent of state). Split-K:
// h = sum of NDS partial planes (independent coalesced loads, unroll 8).
// ---------------------------------------------------------------------------
template <int NDS>
__global__ __launch_bounds__(64) void k3_scan(
    const float* __restrict__ hU, const float* __restrict__ ctx,
    const float* __restrict__ ew, float* __restrict__ out) {
  const int gid = blockIdx.x * 64 + threadIdx.x;  // 0..1791
  const int b = gid / VV;
  const int v = gid - b * VV;
  const float ctxv = ctx[b * VV + v];
  const float e0 = ew[0] + ctxv;
  const float e1 = ew[1] + ctxv;
  constexpr size_t PL = (size_t)TT * BB * VV;  // plane stride
  const float* hp = hU + (size_t)b * VV + v;
  float* op = out + (size_t)b * TT * VV + v;
  bool s;
  {
    // t = 0: h_prev = 0 and y_prev = 0 -> ew[0], no hU term
    const float y = 1.f / (1.f + expf(-e0));
    s = (y == 1.0f);
    op[0] = y;
  }
#pragma unroll 8
  for (int t = 1; t < TT; ++t) {
    float h = 0.f;
#pragma unroll
    for (int p = 0; p < NDS; ++p)
      h += hp[(size_t)p * PL + (size_t)t * (BB * VV)];
    const float c0 = 1.f / (1.f + expf(-(e0 + h)));
    const float c1 = 1.f / (1.f + expf(-(e1 + h)));
    const float y = s ? c1 : c0;
    s = (y == 1.0f);
    op[(size_t)t * VV] = y;
  }
}

// ---------------------------------------------------------------------------
extern "C" void kernel_launch(void* const* d_in, const int* in_sizes, int n_in,
                              void* d_out, int out_size, void* d_ws, size_t ws_size,
                              hipStream_t stream) {
  const float* x   = (const float*)d_in[0];
  // d_in[1]=Wa, d_in[2]=Ua, d_in[3]=Va dead (softmax over size-1 axis == 1)
  const float* Wo  = (const float*)d_in[4];
  const float* Uo  = (const float*)d_in[5];
  const float* Co  = (const float*)d_in[6];
  const float* emb = (const float*)d_in[7];
  float* out = (float*)d_out;

  const size_t PL = (size_t)TT * BB * VV;          // 917504 floats / plane
  const size_t PART = (size_t)BB * 16 * DD;        // 1048576 floats
  const size_t need4 = (4 * PL + PART + BB * VV + 32) * sizeof(float);  // ~18.9MB

  float* ws = (float*)d_ws;
  if (ws_size >= need4) {
    float* hUp  = ws;
    float* part = hUp + 4 * PL;
    float* ctx  = part + PART;
    float* ewp  = ctx + BB * VV;
    k1_hU_rowsum<4><<<512 * 4, 256, 0, stream>>>(x, Uo, hUp, part);
    k2_ctx_ew<<<BB, 256, 0, stream>>>(part, Co, Wo, emb, ctx, ewp);
    k3_scan<4><<<28, 64, 0, stream>>>(hUp, ctx, ewp, out);
  } else {
    float* hUp  = ws;
    float* part = hUp + PL;
    float* ctx  = part + PART;
    float* ewp  = ctx + BB * VV;
    k1_hU_rowsum<1><<<512, 256, 0, stream>>>(x, Uo, hUp, part);
    k2_ctx_ew<<<BB, 256, 0, stream>>>(part, Co, Wo, emb, ctx, ewp);
    k3_scan<1><<<28, 64, 0, stream>>>(hUp, ctx, ewp, out);
  }
}

// Round 5
// 307.490 us; speedup vs baseline: 1.5717x; 1.2314x over previous
//
#include <hip/hip_runtime.h>
#include <cstddef>

// Problem constants
#define BB 64
#define TT 512
#define DD 1024
#define VV 28
#define BV (BB * VV)  // 1792

// ---------------------------------------------------------------------------
// K1: hU[t+1][b][v] = x[b,t,:] @ Uo[:,v]  (full d per block; 32 t-rows/block)
//     part[b*16 + tch][d] = 32-row sums of x (f32, same order as round 4)
// Grid 1024 blocks (b = g>>4, tch = g&15), 256 threads, LDS 16.5 KB ->
// 4 blocks/CU, 16 waves/CU. Hot loop is LDS+FMA only (round-3 lesson: no
// global loads in the FMA chain). Wl reads are wave-quasi-uniform (2 distinct
// 16B addrs/wave) -> LDS broadcast, cheap; xs b128 pattern measured 0 conflicts.
// ---------------------------------------------------------------------------
__global__ __launch_bounds__(256, 4) void k1_hU_rowsum(
    const float* __restrict__ x, const float* __restrict__ Uo,
    float* __restrict__ hU, float* __restrict__ part) {
  __shared__ float xs[32][68];   // stride 68
  __shared__ float Wl[64][32];   // Uo chunk, zero-padded cols 28..31
  const int g   = blockIdx.x;
  const int b   = g >> 4;
  const int tch = g & 15;
  const int t0  = tch << 5;
  const int tid = threadIdx.x;
  const int row = tid & 31;      // compute: t-row
  const int vg  = tid >> 5;      // compute: v-group 0..7 (vg=7 -> padded zeros)
  const int vbase = vg << 2;
  float acc[4] = {0.f, 0.f, 0.f, 0.f};
  const float* xbase = x + (size_t)(b * TT + t0) * DD;

  for (int c = 0; c < 16; ++c) {
    const int d0 = c << 6;
    __syncthreads();             // previous chunk's reads done
    // stage x: 32 rows x 64 d = 512 float4, 2/thread, coalesced
#pragma unroll
    for (int i = 0; i < 2; ++i) {
      const int f = tid + (i << 8);
      const int r = f >> 4;
      const int col = (f & 15) << 2;
      *reinterpret_cast<float4*>(&xs[r][col]) =
          *reinterpret_cast<const float4*>(xbase + (size_t)r * DD + d0 + col);
    }
    // stage Uo chunk 64 x 28 (pad 32): 8 floats/thread; L2-resident source
#pragma unroll
    for (int k = 0; k < 8; ++k) {
      const int idx = tid + (k << 8);
      const int r = idx >> 5, ccol = idx & 31;
      Wl[r][ccol] = (ccol < VV) ? Uo[(size_t)(d0 + r) * VV + ccol] : 0.f;
    }
    __syncthreads();
    // hot loop: per thread 16 x 4 x 4 = 256 FMA per chunk
#pragma unroll 2
    for (int dd = 0; dd < 64; dd += 4) {
      const float4 xv = *reinterpret_cast<const float4*>(&xs[row][dd]);
      const float xq[4] = {xv.x, xv.y, xv.z, xv.w};
#pragma unroll
      for (int q = 0; q < 4; ++q) {
        const float4 wa = *reinterpret_cast<const float4*>(&Wl[dd + q][vbase]);
        acc[0] = fmaf(xq[q], wa.x, acc[0]);
        acc[1] = fmaf(xq[q], wa.y, acc[1]);
        acc[2] = fmaf(xq[q], wa.z, acc[2]);
        acc[3] = fmaf(xq[q], wa.w, acc[3]);
      }
    }
    // rowsum partial (reads xs before next chunk's barrier)
    if (tid < 64) {
      float s = 0.f;
#pragma unroll 8
      for (int r = 0; r < 32; ++r) s += xs[r][tid];
      part[(size_t)(b * 16 + tch) * DD + d0 + tid] = s;
    }
  }
  // epilogue: row t feeds step t+1; t = T-1 discarded; vg=7 is padding
  const int t = t0 + row;
  if (t + 1 < TT && vbase < VV) {
    float* o = hU + (size_t)(t + 1) * BV + b * VV + vbase;
    *reinterpret_cast<float4*>(o) = make_float4(acc[0], acc[1], acc[2], acc[3]);
  }
}

// ---------------------------------------------------------------------------
// K2: ctx[b][v] = (sum_t x[b,t,:]) @ Co[:,v];  ew[j] = emb_table[j,:] @ Wo
// (unchanged; part slot order bit-identical to round 4)
// ---------------------------------------------------------------------------
__global__ __launch_bounds__(256) void k2_ctx_ew(
    const float* __restrict__ part, const float* __restrict__ Co,
    const float* __restrict__ Wo, const float* __restrict__ emb,
    float* __restrict__ ctx, float* __restrict__ ew) {
  __shared__ float rs[DD];
  __shared__ float red[8][32];
  const int b = blockIdx.x;
  const int tid = threadIdx.x;
  for (int d = tid; d < DD; d += 256) {
    float s = 0.f;
#pragma unroll
    for (int k = 0; k < 16; ++k) s += part[(size_t)(b * 16 + k) * DD + d];
    rs[d] = s;
  }
  __syncthreads();
  const int v = tid & 31, seg = tid >> 5;
  float pa = 0.f;
  if (v < VV) {
    const float* cp = Co + (size_t)(seg * 128) * VV + v;
    const float* rp = &rs[seg * 128];
#pragma unroll 4
    for (int d = 0; d < 128; ++d) pa = fmaf(rp[d], cp[(size_t)d * VV], pa);
  }
  red[seg][v] = pa;
  __syncthreads();
  if (tid < 32) {
    float s = 0.f;
#pragma unroll
    for (int k = 0; k < 8; ++k) s += red[k][tid];
    if (tid < VV) ctx[b * VV + tid] = s;
  }
  if (b == 0 && tid >= 64 && tid < 64 + VV) {
    const int j = tid - 64;
    float s = 0.f;
#pragma unroll
    for (int k = 0; k < VV; ++k) s = fmaf(emb[j * VV + k], Wo[k], s);
    ew[j] = s;
  }
}

// ---------------------------------------------------------------------------
// K3a: transition bits, fully parallel. b0/b1 = (sigmoid(e0/1 + h_t) == 1.0f),
// packed per 64-chain group via __ballot into W0/W1[t][28] (uint64).
// Grid 3584 x 256 covers (t-major, bv-minor) exactly; waves never straddle t.
// ---------------------------------------------------------------------------
__global__ __launch_bounds__(256) void k3a_bits(
    const float* __restrict__ hU, const float* __restrict__ ctx,
    const float* __restrict__ ew,
    unsigned long long* __restrict__ W0, unsigned long long* __restrict__ W1) {
  const int flat = blockIdx.x * 256 + threadIdx.x;
  const int t = flat / BV;
  const int bv = flat - t * BV;
  const float ctxv = ctx[bv];
  const float e0 = ew[0] + ctxv;
  const float e1 = ew[1] + ctxv;
  const float h = (t == 0) ? 0.f : hU[(size_t)t * BV + bv];
  const float c0 = 1.f / (1.f + expf(-(e0 + h)));
  const float c1 = 1.f / (1.f + expf(-(e1 + h)));
  const unsigned long long m0 = __ballot(c0 == 1.0f);
  const unsigned long long m1 = __ballot(c1 == 1.0f);
  if ((threadIdx.x & 63) == 0) {
    const int w = bv >> 6;  // 0..27
    W0[t * 28 + w] = m0;
    W1[t * 28 + w] = m1;
  }
}

// ---------------------------------------------------------------------------
// K3b: the only sequential part. Per 64-chain word column j, the whole state
// is ONE uint64: s' = (s & w1) | (~s & w0). 512 pure-ALU steps on LDS-staged
// words; S[t][j] = state BEFORE step t's transition (s_0 = 0).
// ---------------------------------------------------------------------------
__global__ __launch_bounds__(64) void k3b_scan(
    const unsigned long long* __restrict__ W0,
    const unsigned long long* __restrict__ W1,
    unsigned long long* __restrict__ S) {
  __shared__ unsigned long long l0[TT], l1[TT], ls[TT];
  const int j = blockIdx.x;
  const int tid = threadIdx.x;
  for (int t = tid; t < TT; t += 64) {
    l0[t] = W0[t * 28 + j];
    l1[t] = W1[t * 28 + j];
  }
  __syncthreads();
  if (tid == 0) {
    unsigned long long s = 0ull;
#pragma unroll 8
    for (int t = 0; t < TT; ++t) {
      ls[t] = s;
      s = (s & l1[t]) | (~s & l0[t]);
    }
  }
  __syncthreads();
  for (int t = tid; t < TT; t += 64) S[t * 28 + j] = ls[t];
}

// ---------------------------------------------------------------------------
// K3c: output, fully parallel. y = sigmoid((ew[s]+ctx)+h) — same association
// as the round-4 scan -> bit-exact. S word is wave-uniform (broadcast load).
// ---------------------------------------------------------------------------
__global__ __launch_bounds__(256) void k3c_out(
    const float* __restrict__ hU, const float* __restrict__ ctx,
    const float* __restrict__ ew, const unsigned long long* __restrict__ S,
    float* __restrict__ out) {
  const int flat = blockIdx.x * 256 + threadIdx.x;
  const int t = flat / BV;
  const int bv = flat - t * BV;
  const int b = bv / VV;
  const int v = bv - b * VV;
  const float ctxv = ctx[bv];
  const float h = (t == 0) ? 0.f : hU[(size_t)t * BV + bv];
  const unsigned long long w = S[t * 28 + (bv >> 6)];
  const float e = ((w >> (bv & 63)) & 1ull) ? ew[1] : ew[0];
  const float y = 1.f / (1.f + expf(-((e + ctxv) + h)));
  out[(size_t)b * TT * VV + (size_t)t * VV + v] = y;
}

// ---------------------------------------------------------------------------
extern "C" void kernel_launch(void* const* d_in, const int* in_sizes, int n_in,
                              void* d_out, int out_size, void* d_ws, size_t ws_size,
                              hipStream_t stream) {
  const float* x   = (const float*)d_in[0];
  // d_in[1]=Wa, d_in[2]=Ua, d_in[3]=Va dead (softmax over size-1 axis == 1)
  const float* Wo  = (const float*)d_in[4];
  const float* Uo  = (const float*)d_in[5];
  const float* Co  = (const float*)d_in[6];
  const float* emb = (const float*)d_in[7];
  float* out = (float*)d_out;

  float* ws   = (float*)d_ws;
  float* hU   = ws;                              // T*B*V   = 917504 f
  float* part = hU + (size_t)TT * BV;            // B*16*D  = 1048576 f
  float* ctx  = part + (size_t)BB * 16 * DD;     // 1792 f
  float* ewp  = ctx + BV;                        // 32 f
  unsigned long long* W0 = (unsigned long long*)(ewp + 32);  // 8B-aligned
  unsigned long long* W1 = W0 + (size_t)TT * 28;             // 14336 u64 each
  unsigned long long* S  = W1 + (size_t)TT * 28;
  // total ~8.2 MB (< the 18.9 MB already used successfully in round 3)

  k1_hU_rowsum<<<1024, 256, 0, stream>>>(x, Uo, hU, part);
  k2_ctx_ew<<<BB, 256, 0, stream>>>(part, Co, Wo, emb, ctx, ewp);
  k3a_bits<<<3584, 256, 0, stream>>>(hU, ctx, ewp, W0, W1);
  k3b_scan<<<28, 64, 0, stream>>>(W0, W1, S);
  k3c_out<<<3584, 256, 0, stream>>>(hU, ctx, ewp, S, out);
}

// Round 7
// 305.511 us; speedup vs baseline: 1.5819x; 1.0065x over previous
//
#include <hip/hip_runtime.h>
#include <cstddef>

// Problem constants
#define BB 64
#define TT 512
#define DD 1024
#define VV 28
#define BV (BB * VV)  // 1792

// ---------------------------------------------------------------------------
// K1 (split-K over d, NDS planes): block (b, tch, ds) covers 256 t-rows and a
// DD/NDS d-slice. Each THREAD owns one t-row and ALL 28 v:
//   hUp[ds][t+1][b][v] = x[b,t,dslice] @ Uo[dslice,v]
// Round-5 lesson: Uo-in-LDS cost 64 ds_read_b128/wave/chunk of pure issue tax
// (broadcast saves bandwidth, not the ~12cy pipe occupancy) -> kernel was
// LDS-issue-bound at 20% VALUBusy. Now Uo addresses are wave-UNIFORM (loop
// index only) -> compiler emits s_load; FMA takes Uo from SGPRs (0 issue tax).
// LDS carries only xs: 16 b128/thread/chunk vs 1792 FMA.
//   part[b*8 + tch*4 + q][d] = 64-row sums of x (wave q sums rows 64q..64q+63;
//   t-ascending order preserved for k2).
// xs[256][68]: row stride 272B (16B-aligned); b128 lane-per-row reads are
// bank-BALANCED (8 lane-touches x 4B per bank = baseline sweep, no conflict).
// ---------------------------------------------------------------------------
template <int NDS>
__global__ __launch_bounds__(256, 2) void k1_hU_rowsum(
    const float* __restrict__ x, const float* __restrict__ Uo,
    float* __restrict__ hUp, float* __restrict__ part) {
  constexpr int DPB = DD / NDS;   // d's per block
  constexpr int NCH = DPB / 64;   // 64-d chunks
  __shared__ float xs[256][68];
  const int g   = blockIdx.x;
  const int ds  = g % NDS;
  const int r0  = g / NDS;
  const int tch = r0 & 1;
  const int b   = r0 >> 1;
  const int t0  = tch << 8;
  const int tid = threadIdx.x;    // == local t-row
  const int dbase = ds * DPB;
  const float* xbase = x + (size_t)(b * TT + t0) * DD + dbase;
  float acc[VV];
#pragma unroll
  for (int v = 0; v < VV; ++v) acc[v] = 0.f;
  const int rcol = tid & 63;      // rowsum: column
  const int rq   = tid >> 6;      // rowsum: wave q sums rows 64q..64q+63

  for (int c = 0; c < NCH; ++c) {
    const int d0 = c << 6;
    __syncthreads();              // previous chunk's reads done
    // stage 256 rows x 64 d: 16 float4/thread; consecutive tid -> consecutive
    // 16B within a row (256B runs, coalesced)
#pragma unroll
    for (int i = 0; i < 16; ++i) {
      const int f   = tid + (i << 8);
      const int row = f >> 4;
      const int q4  = (f & 15) << 2;
      *reinterpret_cast<float4*>(&xs[row][q4]) =
          *reinterpret_cast<const float4*>(xbase + (size_t)row * DD + d0 + q4);
    }
    __syncthreads();
    // hot loop: x from LDS (own row, b128), Uo via wave-uniform loads (SMEM).
    const float* uo = Uo + (size_t)(dbase + d0) * VV;
#pragma unroll 2
    for (int dd = 0; dd < 64; dd += 4) {
      const float4 xv = *reinterpret_cast<const float4*>(&xs[tid][dd]);
      const float xq[4] = {xv.x, xv.y, xv.z, xv.w};
#pragma unroll
      for (int q = 0; q < 4; ++q) {
        const float* ur = uo + (size_t)(dd + q) * VV;  // uniform, 16B-aligned
#pragma unroll
        for (int v7 = 0; v7 < 7; ++v7) {
          const float4 w = *reinterpret_cast<const float4*>(ur + (v7 << 2));
          acc[v7 * 4 + 0] = fmaf(xq[q], w.x, acc[v7 * 4 + 0]);
          acc[v7 * 4 + 1] = fmaf(xq[q], w.y, acc[v7 * 4 + 1]);
          acc[v7 * 4 + 2] = fmaf(xq[q], w.z, acc[v7 * 4 + 2]);
          acc[v7 * 4 + 3] = fmaf(xq[q], w.w, acc[v7 * 4 + 3]);
        }
      }
    }
    // rowsum partials: wave q sums its 64 rows at column rcol (2-way, free)
    {
      float s = 0.f;
#pragma unroll 8
      for (int r = 0; r < 64; ++r) s += xs[(rq << 6) + r][rcol];
      part[(size_t)(b * 8 + tch * 4 + rq) * DD + dbase + d0 + rcol] = s;
    }
  }
  // epilogue: row t feeds step t+1; t = T-1 discarded
  const int t = t0 + tid;
  if (t + 1 < TT) {
    float* o = hUp + (size_t)ds * TT * BV + (size_t)(t + 1) * BV + b * VV;
#pragma unroll
    for (int v7 = 0; v7 < 7; ++v7)
      *reinterpret_cast<float4*>(o + (v7 << 2)) = make_float4(
          acc[v7 * 4 + 0], acc[v7 * 4 + 1], acc[v7 * 4 + 2], acc[v7 * 4 + 3]);
  }
}

// ---------------------------------------------------------------------------
// K2: ctx[b][v] = (sum_t x[b,t,:]) @ Co[:,v];  ew[j] = emb_table[j,:] @ Wo
// part now has 8 t-ascending slots per b.
// ---------------------------------------------------------------------------
__global__ __launch_bounds__(256) void k2_ctx_ew(
    const float* __restrict__ part, const float* __restrict__ Co,
    const float* __restrict__ Wo, const float* __restrict__ emb,
    float* __restrict__ ctx, float* __restrict__ ew) {
  __shared__ float rs[DD];
  __shared__ float red[8][32];
  const int b = blockIdx.x;
  const int tid = threadIdx.x;
  for (int d = tid; d < DD; d += 256) {
    float s = 0.f;
#pragma unroll
    for (int k = 0; k < 8; ++k) s += part[(size_t)(b * 8 + k) * DD + d];
    rs[d] = s;
  }
  __syncthreads();
  const int v = tid & 31, seg = tid >> 5;
  float pa = 0.f;
  if (v < VV) {
    const float* cp = Co + (size_t)(seg * 128) * VV + v;
    const float* rp = &rs[seg * 128];
#pragma unroll 4
    for (int d = 0; d < 128; ++d) pa = fmaf(rp[d], cp[(size_t)d * VV], pa);
  }
  red[seg][v] = pa;
  __syncthreads();
  if (tid < 32) {
    float s = 0.f;
#pragma unroll
    for (int k = 0; k < 8; ++k) s += red[k][tid];
    if (tid < VV) ctx[b * VV + tid] = s;
  }
  if (b == 0 && tid >= 64 && tid < 64 + VV) {
    const int j = tid - 64;
    float s = 0.f;
#pragma unroll
    for (int k = 0; k < VV; ++k) s = fmaf(emb[j * VV + k], Wo[k], s);
    ew[j] = s;
  }
}

// ---------------------------------------------------------------------------
// K3a: transition bits, fully parallel. h = plane-sum (((p0+p1)+p2)+p3 — same
// association as the round-3 scan, which validated). Ballot-packed to W0/W1.
// ---------------------------------------------------------------------------
template <int NDS>
__global__ __launch_bounds__(256) void k3a_bits(
    const float* __restrict__ hUp, const float* __restrict__ ctx,
    const float* __restrict__ ew,
    unsigned long long* __restrict__ W0, unsigned long long* __restrict__ W1) {
  constexpr size_t PL = (size_t)TT * BV;
  const int flat = blockIdx.x * 256 + threadIdx.x;
  const int t = flat / BV;
  const int bv = flat - t * BV;
  const float ctxv = ctx[bv];
  const float e0 = ew[0] + ctxv;
  const float e1 = ew[1] + ctxv;
  float h = 0.f;
  if (t > 0) {
#pragma unroll
    for (int p = 0; p < NDS; ++p) h += hUp[(size_t)p * PL + (size_t)t * BV + bv];
  }
  const float c0 = 1.f / (1.f + expf(-(e0 + h)));
  const float c1 = 1.f / (1.f + expf(-(e1 + h)));
  const unsigned long long m0 = __ballot(c0 == 1.0f);
  const unsigned long long m1 = __ballot(c1 == 1.0f);
  if ((threadIdx.x & 63) == 0) {
    const int w = bv >> 6;
    W0[t * 28 + w] = m0;
    W1[t * 28 + w] = m1;
  }
}

// ---------------------------------------------------------------------------
// K3b: the only sequential part: per word column, 512 steps of
// s' = (s & w1) | (~s & w0) on LDS-staged words.
// ---------------------------------------------------------------------------
__global__ __launch_bounds__(64) void k3b_scan(
    const unsigned long long* __restrict__ W0,
    const unsigned long long* __restrict__ W1,
    unsigned long long* __restrict__ S) {
  __shared__ unsigned long long l0[TT], l1[TT], ls[TT];
  const int j = blockIdx.x;
  const int tid = threadIdx.x;
  for (int t = tid; t < TT; t += 64) {
    l0[t] = W0[t * 28 + j];
    l1[t] = W1[t * 28 + j];
  }
  __syncthreads();
  if (tid == 0) {
    unsigned long long s = 0ull;
#pragma unroll 8
    for (int t = 0; t < TT; ++t) {
      ls[t] = s;
      s = (s & l1[t]) | (~s & l0[t]);
    }
  }
  __syncthreads();
  for (int t = tid; t < TT; t += 64) S[t * 28 + j] = ls[t];
}

// ---------------------------------------------------------------------------
// K3c: output, fully parallel. y = sigmoid((ew[s]+ctx)+h), h = plane sum.
// ---------------------------------------------------------------------------
template <int NDS>
__global__ __launch_bounds__(256) void k3c_out(
    const float* __restrict__ hUp, const float* __restrict__ ctx,
    const float* __restrict__ ew, const unsigned long long* __restrict__ S,
    float* __restrict__ out) {
  constexpr size_t PL = (size_t)TT * BV;
  const int flat = blockIdx.x * 256 + threadIdx.x;
  const int t = flat / BV;
  const int bv = flat - t * BV;
  const int b = bv / VV;
  const int v = bv - b * VV;
  const float ctxv = ctx[bv];
  float h = 0.f;
  if (t > 0) {
#pragma unroll
    for (int p = 0; p < NDS; ++p) h += hUp[(size_t)p * PL + (size_t)t * BV + bv];
  }
  const unsigned long long w = S[t * 28 + (bv >> 6)];
  const float e = ((w >> (bv & 63)) & 1ull) ? ew[1] : ew[0];
  const float y = 1.f / (1.f + expf(-((e + ctxv) + h)));
  out[(size_t)b * TT * VV + (size_t)t * VV + v] = y;
}

// ---------------------------------------------------------------------------
extern "C" void kernel_launch(void* const* d_in, const int* in_sizes, int n_in,
                              void* d_out, int out_size, void* d_ws, size_t ws_size,
                              hipStream_t stream) {
  const float* x   = (const float*)d_in[0];
  // d_in[1]=Wa, d_in[2]=Ua, d_in[3]=Va dead (softmax over size-1 axis == 1)
  const float* Wo  = (const float*)d_in[4];
  const float* Uo  = (const float*)d_in[5];
  const float* Co  = (const float*)d_in[6];
  const float* emb = (const float*)d_in[7];
  float* out = (float*)d_out;

  const size_t PL   = (size_t)TT * BV;      // 917504 floats / plane
  const size_t PART = (size_t)BB * 8 * DD;  // 524288 floats
  const size_t need4 =
      (4 * PL + PART + BV + 32) * sizeof(float) + 3 * (size_t)TT * 28 * 8;

  float* ws = (float*)d_ws;
  if (ws_size >= need4) {
    float* hUp  = ws;
    float* part = hUp + 4 * PL;
    float* ctx  = part + PART;
    float* ewp  = ctx + BV;
    unsigned long long* W0 = (unsigned long long*)(ewp + 32);
    unsigned long long* W1 = W0 + (size_t)TT * 28;
    unsigned long long* S  = W1 + (size_t)TT * 28;
    k1_hU_rowsum<4><<<64 * 2 * 4, 256, 0, stream>>>(x, Uo, hUp, part);
    k2_ctx_ew<<<BB, 256, 0, stream>>>(part, Co, Wo, emb, ctx, ewp);
    k3a_bits<4><<<3584, 256, 0, stream>>>(hUp, ctx, ewp, W0, W1);
    k3b_scan<<<28, 64, 0, stream>>>(W0, W1, S);
    k3c_out<4><<<3584, 256, 0, stream>>>(hUp, ctx, ewp, S, out);
  } else {
    float* hUp  = ws;
    float* part = hUp + PL;
    float* ctx  = part + PART;
    float* ewp  = ctx + BV;
    unsigned long long* W0 = (unsigned long long*)(ewp + 32);
    unsigned long long* W1 = W0 + (size_t)TT * 28;
    unsigned long long* S  = W1 + (size_t)TT * 28;
    k1_hU_rowsum<1><<<64 * 2, 256, 0, stream>>>(x, Uo, hUp, part);
    k2_ctx_ew<<<BB, 256, 0, stream>>>(part, Co, Wo, emb, ctx, ewp);
    k3a_bits<1><<<3584, 256, 0, stream>>>(hUp, ctx, ewp, W0, W1);
    k3b_scan<<<28, 64, 0, stream>>>(W0, W1, S);
    k3c_out<1><<<3584, 256, 0, stream>>>(hUp, ctx, ewp, S, out);
  }
}

// Round 11
// 254.338 us; speedup vs baseline: 1.9002x; 1.2012x over previous
//
#include <hip/hip_runtime.h>
#include <cstddef>

// Problem constants
#define BB 64
#define TT 512
#define DD 1024
#define VV 28
#define BV (BB * VV)  // 1792

typedef float f32x4 __attribute__((ext_vector_type(4)));
typedef short bf16x8 __attribute__((ext_vector_type(8)));

static __device__ __forceinline__ ushort f2bf(float f) {
  unsigned u = __float_as_uint(f);
  unsigned r = (u + 0x7FFF + ((u >> 16) & 1)) >> 16;  // RNE
  return (ushort)r;
}

// ---------------------------------------------------------------------------
// K0: pack Uo [1024][28] fp32 -> Ubf [32][1024] bf16 (transposed, v-padded 0)
// ---------------------------------------------------------------------------
__global__ __launch_bounds__(256) void k0_packB(const float* __restrict__ Uo,
                                                ushort* __restrict__ Ubf) {
  const int idx = blockIdx.x * 256 + threadIdx.x;  // 0..32767
  const int v = idx >> 10, k = idx & 1023;
  const float f = (v < VV) ? Uo[(size_t)k * VV + v] : 0.f;
  Ubf[idx] = f2bf(f);
}

// ---------------------------------------------------------------------------
// K1 (MFMA bf16): block (b, tch) computes hU[t+1][b][v] = x[b,t,:] @ Uo[:,v]
// for 64 t-rows, all v. Rounds 4/5/7 lesson: scalar-fp32-through-LDS caps at
// ~25-40% VALU (2 floats/FMA vs 4 floats per 12cy ds_read_b128) -> ~110us
// wall whichever pipe carries B. MFMA: 16 KFLOP per ~3 ds_reads.
//  - K in 8 chunks of 128, double-buffered LDS, loads issued before MFMA phase
//  - A[64][128] bf16 XOR-swizzled (byte ^= (row&7)<<4, G4); B[32][128] same
//  - rowsum computed fp32-exact from staging registers (ctx path unchanged);
//    part[b*8+tch][d], 8 ascending 64-row slots (k2-compatible)
// LDS 52 KB -> 3 blocks/CU; grid 512 -> 2 resident/CU; dbuf hides staging.
// ---------------------------------------------------------------------------
__global__ __launch_bounds__(256, 2) void k1_mfma(
    const float* __restrict__ x, const ushort* __restrict__ Ubf,
    float* __restrict__ hU, float* __restrict__ part) {
  __shared__ ushort Ab[2][64 * 128];  // 16 KB each, swizzled [row][k]
  __shared__ ushort Bb[2][32 * 128];  // 8 KB each, swizzled [v][k]
  __shared__ float rsum[8][128];
  const int g = blockIdx.x, b = g >> 3, tch = g & 7;
  const int tid = threadIdx.x;
  const int w = tid >> 6, l = tid & 63;
  const float* xbase = x + (size_t)(b * TT + tch * 64) * DD;
  // staging indices (A): thread loads rows srow0+8i at fixed 4-float column
  const int srow0 = tid >> 5;
  const int scol4 = (tid & 31) << 2;
  // staging indices (B): thread loads 16 bf16 of one v-row
  const int bv_ = tid >> 3;
  const int bseg = (tid & 7) << 4;
  // fragment addresses: A row = 16w + (l&15); B cols l&15 / 16+(l&15)
  const int arow = 16 * w + (l & 15);
  const int aswz = (arow & 7) << 4;
  const int bcol0 = l & 15, bcol1 = 16 + (l & 15);
  const int bswz0 = (bcol0 & 7) << 4, bswz1 = (bcol1 & 7) << 4;
  const int kg16 = (l >> 4) << 4;  // k-group byte offset within k-step

  f32x4 acc0 = {0.f, 0.f, 0.f, 0.f}, acc1 = {0.f, 0.f, 0.f, 0.f};
  float4 ld[8];
  uint4 bl0, bl1;

#define ISSUE(c)                                                              \
  {                                                                           \
    const float* p = xbase + (c) * 128;                                       \
    _Pragma("unroll") for (int i = 0; i < 8; ++i) {                           \
      ld[i] = *reinterpret_cast<const float4*>(                               \
          p + (size_t)(srow0 + 8 * i) * DD + scol4);                          \
    }                                                                         \
    const ushort* q = Ubf + bv_ * 1024 + (c) * 128 + bseg;                    \
    bl0 = *reinterpret_cast<const uint4*>(q);                                 \
    bl1 = *reinterpret_cast<const uint4*>(q + 8);                             \
  }

#define WRITE(buf)                                                            \
  {                                                                           \
    float4 ps = make_float4(0.f, 0.f, 0.f, 0.f);                              \
    _Pragma("unroll") for (int i = 0; i < 8; ++i) {                           \
      ps.x += ld[i].x; ps.y += ld[i].y; ps.z += ld[i].z; ps.w += ld[i].w;     \
      const int row = srow0 + 8 * i;                                          \
      ushort4 hv;                                                             \
      hv.x = f2bf(ld[i].x); hv.y = f2bf(ld[i].y);                             \
      hv.z = f2bf(ld[i].z); hv.w = f2bf(ld[i].w);                             \
      *reinterpret_cast<ushort4*>(                                            \
          (char*)&Ab[buf][0] + ((row * 256 + scol4 * 2) ^ ((row & 7) << 4))) = \
          hv;                                                                 \
    }                                                                         \
    *reinterpret_cast<uint4*>(                                                \
        (char*)&Bb[buf][0] + ((bv_ * 256 + bseg * 2) ^ ((bv_ & 7) << 4))) =   \
        bl0;                                                                  \
    *reinterpret_cast<uint4*>(                                                \
        (char*)&Bb[buf][0] +                                                  \
        ((bv_ * 256 + bseg * 2 + 16) ^ ((bv_ & 7) << 4))) = bl1;              \
    *reinterpret_cast<float4*>(&rsum[srow0][scol4]) = ps;                     \
  }

#define REDUCE(c)                                                             \
  if (tid < 128) {                                                            \
    float s_ = 0.f;                                                           \
    _Pragma("unroll") for (int g2 = 0; g2 < 8; ++g2) s_ += rsum[g2][tid];     \
    part[(size_t)(b * 8 + tch) * DD + (c) * 128 + tid] = s_;                  \
  }

#define COMPUTE(cb)                                                           \
  {                                                                           \
    _Pragma("unroll") for (int s = 0; s < 4; ++s) {                           \
      const int kb = s * 64 + kg16;                                           \
      bf16x8 af = *reinterpret_cast<const bf16x8*>(                           \
          (const char*)&Ab[cb][0] + ((arow * 256 + kb) ^ aswz));              \
      bf16x8 b0f = *reinterpret_cast<const bf16x8*>(                          \
          (const char*)&Bb[cb][0] + ((bcol0 * 256 + kb) ^ bswz0));            \
      bf16x8 b1f = *reinterpret_cast<const bf16x8*>(                          \
          (const char*)&Bb[cb][0] + ((bcol1 * 256 + kb) ^ bswz1));            \
      acc0 = __builtin_amdgcn_mfma_f32_16x16x32_bf16(af, b0f, acc0, 0, 0, 0); \
      acc1 = __builtin_amdgcn_mfma_f32_16x16x32_bf16(af, b1f, acc1, 0, 0, 0); \
    }                                                                         \
  }

  // prologue: chunk 0
  ISSUE(0);
  WRITE(0);
  __syncthreads();
  REDUCE(0);
  // main loop: issue c+1 early (T14), compute c, write c+1 behind barrier
  for (int c = 0; c < 8; ++c) {
    if (c < 7) ISSUE(c + 1);
    COMPUTE(c & 1);
    if (c < 7) {
      __syncthreads();
      WRITE((c + 1) & 1);
      __syncthreads();
      REDUCE(c + 1);
    }
  }

  // epilogue: C/D layout (m89-verified): col = l&15, row = (l>>4)*4 + r
  const int tb = tch * 64 + 16 * w + ((l >> 4) << 2);
  const int v0 = l & 15;
#pragma unroll
  for (int r = 0; r < 4; ++r) {
    const int t = tb + r;
    if (t + 1 < TT) {
      float* o = hU + (size_t)(t + 1) * BV + b * VV;
      o[v0] = acc0[r];
      if (v0 + 16 < VV) o[v0 + 16] = acc1[r];
    }
  }
#undef ISSUE
#undef WRITE
#undef REDUCE
#undef COMPUTE
}

// ---------------------------------------------------------------------------
// K2: ctx[b][v] = (sum_t x[b,t,:]) @ Co[:,v];  ew[j] = emb_table[j,:] @ Wo
// part: 8 t-ascending 64-row slots per b (fp32-exact).
// ---------------------------------------------------------------------------
__global__ __launch_bounds__(256) void k2_ctx_ew(
    const float* __restrict__ part, const float* __restrict__ Co,
    const float* __restrict__ Wo, const float* __restrict__ emb,
    float* __restrict__ ctx, float* __restrict__ ew) {
  __shared__ float rs[DD];
  __shared__ float red[8][32];
  const int b = blockIdx.x;
  const int tid = threadIdx.x;
  for (int d = tid; d < DD; d += 256) {
    float s = 0.f;
#pragma unroll
    for (int k = 0; k < 8; ++k) s += part[(size_t)(b * 8 + k) * DD + d];
    rs[d] = s;
  }
  __syncthreads();
  const int v = tid & 31, seg = tid >> 5;
  float pa = 0.f;
  if (v < VV) {
    const float* cp = Co + (size_t)(seg * 128) * VV + v;
    const float* rp = &rs[seg * 128];
#pragma unroll 4
    for (int d = 0; d < 128; ++d) pa = fmaf(rp[d], cp[(size_t)d * VV], pa);
  }
  red[seg][v] = pa;
  __syncthreads();
  if (tid < 32) {
    float s = 0.f;
#pragma unroll
    for (int k = 0; k < 8; ++k) s += red[k][tid];
    if (tid < VV) ctx[b * VV + tid] = s;
  }
  if (b == 0 && tid >= 64 && tid < 64 + VV) {
    const int j = tid - 64;
    float s = 0.f;
#pragma unroll
    for (int k = 0; k < VV; ++k) s = fmaf(emb[j * VV + k], Wo[k], s);
    ew[j] = s;
  }
}

// ---------------------------------------------------------------------------
// K3a: transition bits (fully parallel), ballot-packed into W0/W1[t][28].
// ---------------------------------------------------------------------------
__global__ __launch_bounds__(256) void k3a_bits(
    const float* __restrict__ hU, const float* __restrict__ ctx,
    const float* __restrict__ ew,
    unsigned long long* __restrict__ W0, unsigned long long* __restrict__ W1) {
  const int flat = blockIdx.x * 256 + threadIdx.x;
  const int t = flat / BV;
  const int bv = flat - t * BV;
  const float ctxv = ctx[bv];
  const float e0 = ew[0] + ctxv;
  const float e1 = ew[1] + ctxv;
  const float h = (t == 0) ? 0.f : hU[(size_t)t * BV + bv];
  const float c0 = 1.f / (1.f + expf(-(e0 + h)));
  const float c1 = 1.f / (1.f + expf(-(e1 + h)));
  const unsigned long long m0 = __ballot(c0 == 1.0f);
  const unsigned long long m1 = __ballot(c1 == 1.0f);
  if ((threadIdx.x & 63) == 0) {
    const int wq = bv >> 6;
    W0[t * 28 + wq] = m0;
    W1[t * 28 + wq] = m1;
  }
}

// ---------------------------------------------------------------------------
// K3b: the only sequential part: per 64-chain word, 512 steps of
// s' = (s & w1) | (~s & w0) on LDS-staged words.
// ---------------------------------------------------------------------------
__global__ __launch_bounds__(64) void k3b_scan(
    const unsigned long long* __restrict__ W0,
    const unsigned long long* __restrict__ W1,
    unsigned long long* __restrict__ S) {
  __shared__ unsigned long long l0[TT], l1[TT], ls[TT];
  const int j = blockIdx.x;
  const int tid = threadIdx.x;
  for (int t = tid; t < TT; t += 64) {
    l0[t] = W0[t * 28 + j];
    l1[t] = W1[t * 28 + j];
  }
  __syncthreads();
  if (tid == 0) {
    unsigned long long s = 0ull;
#pragma unroll 8
    for (int t = 0; t < TT; ++t) {
      ls[t] = s;
      s = (s & l1[t]) | (~s & l0[t]);
    }
  }
  __syncthreads();
  for (int t = tid; t < TT; t += 64) S[t * 28 + j] = ls[t];
}

// ---------------------------------------------------------------------------
// K3c: output (fully parallel): y = sigmoid((ew[s]+ctx)+h).
// ---------------------------------------------------------------------------
__global__ __launch_bounds__(256) void k3c_out(
    const float* __restrict__ hU, const float* __restrict__ ctx,
    const float* __restrict__ ew, const unsigned long long* __restrict__ S,
    float* __restrict__ out) {
  const int flat = blockIdx.x * 256 + threadIdx.x;
  const int t = flat / BV;
  const int bv = flat - t * BV;
  const int b = bv / VV;
  const int v = bv - b * VV;
  const float ctxv = ctx[bv];
  const float h = (t == 0) ? 0.f : hU[(size_t)t * BV + bv];
  const unsigned long long wq = S[t * 28 + (bv >> 6)];
  const float e = ((wq >> (bv & 63)) & 1ull) ? ew[1] : ew[0];
  const float y = 1.f / (1.f + expf(-((e + ctxv) + h)));
  out[(size_t)b * TT * VV + (size_t)t * VV + v] = y;
}

// ---------------------------------------------------------------------------
extern "C" void kernel_launch(void* const* d_in, const int* in_sizes, int n_in,
                              void* d_out, int out_size, void* d_ws, size_t ws_size,
                              hipStream_t stream) {
  const float* x   = (const float*)d_in[0];
  // d_in[1]=Wa, d_in[2]=Ua, d_in[3]=Va dead (softmax over size-1 axis == 1)
  const float* Wo  = (const float*)d_in[4];
  const float* Uo  = (const float*)d_in[5];
  const float* Co  = (const float*)d_in[6];
  const float* emb = (const float*)d_in[7];
  float* out = (float*)d_out;

  float* ws   = (float*)d_ws;
  float* hU   = ws;                              // T*B*V  = 917504 f
  float* part = hU + (size_t)TT * BV;            // B*8*D  = 524288 f
  float* ctx  = part + (size_t)BB * 8 * DD;      // 1792 f
  float* ewp  = ctx + BV;                        // 32 f
  unsigned long long* W0 = (unsigned long long*)(ewp + 32);  // 8B-aligned
  unsigned long long* W1 = W0 + (size_t)TT * 28;
  unsigned long long* S  = W1 + (size_t)TT * 28;
  ushort* Ubf = (ushort*)(S + (size_t)TT * 28);  // 32*1024 bf16
  // total ~6.2 MB (18.9 MB fit in round 3)

  k0_packB<<<128, 256, 0, stream>>>(Uo, Ubf);
  k1_mfma<<<512, 256, 0, stream>>>(x, Ubf, hU, part);
  k2_ctx_ew<<<BB, 256, 0, stream>>>(part, Co, Wo, emb, ctx, ewp);
  k3a_bits<<<3584, 256, 0, stream>>>(hU, ctx, ewp, W0, W1);
  k3b_scan<<<28, 64, 0, stream>>>(W0, W1, S);
  k3c_out<<<3584, 256, 0, stream>>>(hU, ctx, ewp, S, out);
}